// Round 5
// baseline (304.080 us; speedup 1.0000x reference)
//
#include <hip/hip_runtime.h>
#include <math.h>

#define L 2048
#define NB 16
#define THREADS 512
#define BLOCKS_PER_BATCH 16                       // 16 batches * 16 = 256 blocks = 1/CU
#define ROWS_PER_BLOCK (L / BLOCKS_PER_BATCH)     // 128 consecutive rows = 1 MiB contiguous
#define GAF_EPS 1e-8f

// native clang vector type: __builtin_nontemporal_store requires this
typedef float f32x4 __attribute__((ext_vector_type(4)));

// ============================================================================
// ROUND-4 MEASUREMENT PROBE — NOT AN OPTIMIZATION.
// v1/v2/v3 (cached vs nt stores, 8 vs 1 blocks/CU, interleaved vs sequential
// writes) all produced identical dur_us residuals (~92 us) — suspicious.
// The residual may be harness overhead (SDMA output copy is invisible to the
// kernel-counter table). This probe launches the IDENTICAL v3 kernel with
// gridDim.y=2: both slices write bitwise-identical data (benign overlap), so
// kernel work is exactly 2x. dur_us(probe) - 260.6 = true kernel duration K.
//   K~92  -> write-pinning theory confirmed; kernel enters top-5 w/ counters
//   K~45  -> kernel already near the 41 us write roofline
//   K<20  -> residual is harness overhead; restore single-pass and stop
// ============================================================================
__global__ __launch_bounds__(THREADS) void gaf_kernel(const float* __restrict__ x,
                                                      float* __restrict__ out) {
    __shared__ float sc[L];    // c_i per row of this batch
    __shared__ float ss[L];    // s_i per row
    __shared__ float red[16];  // 8 waves: min in [0..7], max in [8..15]

    const int b = blockIdx.x / BLOCKS_PER_BATCH;
    const int q = blockIdx.x % BLOCKS_PER_BATCH;
    const int t = threadIdx.x;
    // blockIdx.y in {0,1}: both slices do identical work (calibrated 2x probe)

    // --- load 4 elements/thread as one float4 (whole batch row, coalesced) ---
    const f32x4 v = ((const f32x4*)(x + (size_t)b * L))[t];
    float mn = fminf(fminf(v.x, v.y), fminf(v.z, v.w));
    float mx = fmaxf(fmaxf(v.x, v.y), fmaxf(v.z, v.w));

    // wave-level xor butterfly (all 64 lanes end with the result)
#pragma unroll
    for (int off = 32; off > 0; off >>= 1) {
        mn = fminf(mn, __shfl_xor(mn, off));
        mx = fmaxf(mx, __shfl_xor(mx, off));
    }
    const int wave = t >> 6;
    if ((t & 63) == 0) { red[wave] = mn; red[8 + wave] = mx; }
    __syncthreads();
    mn = red[0];
    mx = red[8];
#pragma unroll
    for (int w = 1; w < 8; ++w) {
        mn = fminf(mn, red[w]);
        mx = fmaxf(mx, red[8 + w]);
    }
    const float inv = 1.0f / (mx - mn + GAF_EPS);

    // --- c,s for this thread's 4 columns: registers + publish to LDS ---
    f32x4 c4, s4;
    {
        float cv[4] = {v.x, v.y, v.z, v.w};
#pragma unroll
        for (int k = 0; k < 4; ++k) {
            float c = 2.0f * ((cv[k] - mn) * inv) - 1.0f;
            c = fminf(fmaxf(c, -1.0f + GAF_EPS), 1.0f - GAF_EPS);
            cv[k] = c;
        }
        c4.x = cv[0]; c4.y = cv[1]; c4.z = cv[2]; c4.w = cv[3];
        s4.x = sqrtf(fmaxf(1.0f - c4.x * c4.x, 0.0f));
        s4.y = sqrtf(fmaxf(1.0f - c4.y * c4.y, 0.0f));
        s4.z = sqrtf(fmaxf(1.0f - c4.z * c4.z, 0.0f));
        s4.w = sqrtf(fmaxf(1.0f - c4.w * c4.w, 0.0f));
    }
    ((f32x4*)sc)[t] = c4;
    ((f32x4*)ss)[t] = s4;
    __syncthreads();

    // --- sweep 128 CONSECUTIVE rows (1 MiB contiguous, strictly sequential) ---
    float* __restrict__ obase =
        out + ((size_t)b * L + (size_t)q * ROWS_PER_BLOCK) * L;
#pragma unroll 8
    for (int m = 0; m < ROWS_PER_BLOCK; ++m) {
        const int r = q * ROWS_PER_BLOCK + m;
        const float ci = sc[r];   // same-address broadcast: conflict-free
        const float si = ss[r];
        f32x4 o;
        o.x = ci * c4.x - si * s4.x;
        o.y = ci * c4.y - si * s4.y;
        o.z = ci * c4.z - si * s4.z;
        o.w = ci * c4.w - si * s4.w;
        __builtin_nontemporal_store(o, (f32x4*)(obase + (size_t)m * L) + t);
    }
}

extern "C" void kernel_launch(void* const* d_in, const int* in_sizes, int n_in,
                              void* d_out, int out_size, void* d_ws, size_t ws_size,
                              hipStream_t stream) {
    const float* x = (const float*)d_in[0];
    float* out = (float*)d_out;
    // PROBE: y-dim = 2 doubles the kernel's work with identical output bytes.
    const dim3 grid(NB * BLOCKS_PER_BATCH, 2);
    gaf_kernel<<<grid, THREADS, 0, stream>>>(x, out);
}

// Round 6
// 260.605 us; speedup vs baseline: 1.1668x; 1.1668x over previous
//
#include <hip/hip_runtime.h>
#include <math.h>

#define L 2048
#define NB 16
#define THREADS 512
#define BLOCKS_PER_BATCH 16                       // 16 batches * 16 = 256 blocks = 1/CU
#define ROWS_PER_BLOCK (L / BLOCKS_PER_BATCH)     // 128 consecutive rows = 1 MiB contiguous
#define GAF_EPS 1e-8f

// native clang vector type: __builtin_nontemporal_store requires this
typedef float f32x4 __attribute__((ext_vector_type(4)));

// gaf[b,i,j] = cos(phi_i + phi_j) = c_i*c_j - s_i*s_j
// with c = clip(2*(x-min)/(max-min+eps) - 1), s = sqrt(1 - c^2).
//
// ROOFLINE NOTE (round-5 calibrated probe): a 2x-work launch measured the
// true kernel cost at 43.5 us = 256 MiB output at ~6.2 TB/s, ~97% of the
// harness fill's own streaming rate (6.4 TB/s). The remaining bench time
// (~217 us) is harness: 1 GiB re-poison fill (~167 us) + output SDMA copy +
// reset memsets — invisible to kernel counters and not addressable from
// kernel source. This kernel is at the write-bandwidth roofline.
__global__ __launch_bounds__(THREADS) void gaf_kernel(const float* __restrict__ x,
                                                      float* __restrict__ out) {
    __shared__ float sc[L];    // c_i per row of this batch
    __shared__ float ss[L];    // s_i per row
    __shared__ float red[16];  // 8 waves: min in [0..7], max in [8..15]

    const int b = blockIdx.x / BLOCKS_PER_BATCH;
    const int q = blockIdx.x % BLOCKS_PER_BATCH;
    const int t = threadIdx.x;

    // --- load 4 elements/thread as one float4 (whole batch row, coalesced) ---
    const f32x4 v = ((const f32x4*)(x + (size_t)b * L))[t];
    float mn = fminf(fminf(v.x, v.y), fminf(v.z, v.w));
    float mx = fmaxf(fmaxf(v.x, v.y), fmaxf(v.z, v.w));

    // wave-level xor butterfly (all 64 lanes end with the result)
#pragma unroll
    for (int off = 32; off > 0; off >>= 1) {
        mn = fminf(mn, __shfl_xor(mn, off));
        mx = fmaxf(mx, __shfl_xor(mx, off));
    }
    const int wave = t >> 6;
    if ((t & 63) == 0) { red[wave] = mn; red[8 + wave] = mx; }
    __syncthreads();
    mn = red[0];
    mx = red[8];
#pragma unroll
    for (int w = 1; w < 8; ++w) {
        mn = fminf(mn, red[w]);
        mx = fmaxf(mx, red[8 + w]);
    }
    const float inv = 1.0f / (mx - mn + GAF_EPS);

    // --- c,s for this thread's 4 columns: keep in registers (these ARE the
    //     cj/sj this thread needs for every row), publish to LDS for the
    //     per-row broadcasts ---
    f32x4 c4, s4;
    {
        float cv[4] = {v.x, v.y, v.z, v.w};
#pragma unroll
        for (int k = 0; k < 4; ++k) {
            float c = 2.0f * ((cv[k] - mn) * inv) - 1.0f;
            c = fminf(fmaxf(c, -1.0f + GAF_EPS), 1.0f - GAF_EPS);
            cv[k] = c;
        }
        c4.x = cv[0]; c4.y = cv[1]; c4.z = cv[2]; c4.w = cv[3];
        s4.x = sqrtf(fmaxf(1.0f - c4.x * c4.x, 0.0f));
        s4.y = sqrtf(fmaxf(1.0f - c4.y * c4.y, 0.0f));
        s4.z = sqrtf(fmaxf(1.0f - c4.z * c4.z, 0.0f));
        s4.w = sqrtf(fmaxf(1.0f - c4.w * c4.w, 0.0f));
    }
    ((f32x4*)sc)[t] = c4;
    ((f32x4*)ss)[t] = s4;
    __syncthreads();

    // --- sweep 128 CONSECUTIVE rows (1 MiB contiguous, strictly sequential).
    //     Per row: 2 broadcast LDS reads + 8 VALU + 1 nt dwordx4 store. ---
    float* __restrict__ obase =
        out + ((size_t)b * L + (size_t)q * ROWS_PER_BLOCK) * L;
#pragma unroll 8
    for (int m = 0; m < ROWS_PER_BLOCK; ++m) {
        const int r = q * ROWS_PER_BLOCK + m;
        const float ci = sc[r];   // same-address broadcast: conflict-free
        const float si = ss[r];
        f32x4 o;
        o.x = ci * c4.x - si * s4.x;
        o.y = ci * c4.y - si * s4.y;
        o.z = ci * c4.z - si * s4.z;
        o.w = ci * c4.w - si * s4.w;
        __builtin_nontemporal_store(o, (f32x4*)(obase + (size_t)m * L) + t);
    }
}

extern "C" void kernel_launch(void* const* d_in, const int* in_sizes, int n_in,
                              void* d_out, int out_size, void* d_ws, size_t ws_size,
                              hipStream_t stream) {
    const float* x = (const float*)d_in[0];
    float* out = (float*)d_out;
    const dim3 grid(NB * BLOCKS_PER_BATCH);  // 256 blocks, one per CU
    gaf_kernel<<<grid, THREADS, 0, stream>>>(x, out);
}